// Round 1
// baseline (49.610 us; speedup 1.0000x reference)
//
#include <hip/hip_runtime.h>

#define VEC_D   128
#define N_WORDS 100000
#define BATCH   16384
#define CTX     8
#define NS      16

// ---------------------------------------------------------------------------
// Kernel 1: transpose outputs [128, N_WORDS] -> outT [N_WORDS, 128]
// Tile = 32 words x all 128 d. N_WORDS = 3125 * 32 exactly (no bounds checks).
// Read coalesced along words, write coalesced along d (float4).
// ---------------------------------------------------------------------------
__global__ __launch_bounds__(256) void transpose_kernel(
    const float* __restrict__ src,   // [128][N_WORDS]
    float* __restrict__ dst)         // [N_WORDS][128]
{
    __shared__ float lds[32][VEC_D + 1];  // [w][d], +1 pad -> stride 129 (conflict-free writes)
    const int tid = threadIdx.x;
    const int w0  = blockIdx.x * 32;

    // Read phase: 16 passes, 8 d-rows per pass, 32 words wide.
    #pragma unroll
    for (int p = 0; p < 16; ++p) {
        const int d = p * 8 + (tid >> 5);
        const int w = tid & 31;
        lds[w][d] = src[(size_t)d * N_WORDS + w0 + w];
    }
    __syncthreads();

    // Write phase: 4 passes, 8 words per pass, each lane writes a float4 of d.
    #pragma unroll
    for (int p = 0; p < 4; ++p) {
        const int wl = p * 8 + (tid >> 5);
        const int d4 = (tid & 31) * 4;
        float4 v = make_float4(lds[wl][d4], lds[wl][d4 + 1],
                               lds[wl][d4 + 2], lds[wl][d4 + 3]);
        *(float4*)&dst[(size_t)(w0 + wl) * VEC_D + d4] = v;
    }
}

// ---------------------------------------------------------------------------
// Kernel 2: main compute. Half-wave (32 lanes) per batch row; lane holds a
// float4 slice (d = 4*l .. 4*l+3). 9 row gathers build the input vector;
// 16 column gathers (from outT, contiguous) + shfl_xor reduction give dots.
// ---------------------------------------------------------------------------
template <bool TRANSPOSED>
__global__ __launch_bounds__(256) void dm_kernel(
    const int*   __restrict__ doc_ids,
    const int*   __restrict__ context_ids,
    const int*   __restrict__ sample_ids,
    const float* __restrict__ pm,      // [N_DOCS][128]
    const float* __restrict__ wm,      // [N_WORDS][128]
    const float* __restrict__ outsrc,  // TRANSPOSED ? outT [N_WORDS][128] : outputs [128][N_WORDS]
    float*       __restrict__ out)     // [BATCH][NS]
{
    const int tid  = threadIdx.x;
    const int wave = tid >> 6;
    const int lane = tid & 63;
    const int half = lane >> 5;      // 0 or 1
    const int l    = lane & 31;      // lane within half
    const int b    = blockIdx.x * 8 + wave * 2 + half;
    const int d0   = l * 4;

    // Build input vector slice: pm[doc] + sum_c wm[ctx[c]]
    const int doc = doc_ids[b];
    float4 v = *(const float4*)&pm[(size_t)doc * VEC_D + d0];
    #pragma unroll
    for (int c = 0; c < CTX; ++c) {
        const int wid = context_ids[b * CTX + c];
        const float4 w4 = *(const float4*)&wm[(size_t)wid * VEC_D + d0];
        v.x += w4.x; v.y += w4.y; v.z += w4.z; v.w += w4.w;
    }

    float res = 0.0f;
    #pragma unroll
    for (int s = 0; s < NS; ++s) {
        const int wid = sample_ids[b * NS + s];
        float acc;
        if (TRANSPOSED) {
            const float4 o4 = *(const float4*)&outsrc[(size_t)wid * VEC_D + d0];
            acc = v.x * o4.x + v.y * o4.y + v.z * o4.z + v.w * o4.w;
        } else {
            acc = v.x * outsrc[(size_t)(d0 + 0) * N_WORDS + wid]
                + v.y * outsrc[(size_t)(d0 + 1) * N_WORDS + wid]
                + v.z * outsrc[(size_t)(d0 + 2) * N_WORDS + wid]
                + v.w * outsrc[(size_t)(d0 + 3) * N_WORDS + wid];
        }
        // Butterfly reduce across the 32-lane half (xor offsets < 32 stay inside it).
        #pragma unroll
        for (int off = 16; off; off >>= 1)
            acc += __shfl_xor(acc, off, 64);
        if (l == s) res = acc;   // lane s keeps sample s's result
    }
    if (l < NS)
        out[(size_t)b * NS + l] = res;  // coalesced 64B store per half-wave
}

extern "C" void kernel_launch(void* const* d_in, const int* in_sizes, int n_in,
                              void* d_out, int out_size, void* d_ws, size_t ws_size,
                              hipStream_t stream) {
    const int*   doc_ids     = (const int*)d_in[0];
    const int*   context_ids = (const int*)d_in[1];
    const int*   sample_ids  = (const int*)d_in[2];
    const float* pm          = (const float*)d_in[3];
    const float* wm          = (const float*)d_in[4];
    const float* outputs     = (const float*)d_in[5];
    float*       out         = (float*)d_out;

    const size_t transposed_bytes = (size_t)N_WORDS * VEC_D * sizeof(float);

    if (ws_size >= transposed_bytes) {
        float* outT = (float*)d_ws;
        transpose_kernel<<<N_WORDS / 32, 256, 0, stream>>>(outputs, outT);
        dm_kernel<true><<<BATCH / 8, 256, 0, stream>>>(
            doc_ids, context_ids, sample_ids, pm, wm, outT, out);
    } else {
        dm_kernel<false><<<BATCH / 8, 256, 0, stream>>>(
            doc_ids, context_ids, sample_ids, pm, wm, outputs, out);
    }
}